// Round 4
// baseline (394.979 us; speedup 1.0000x reference)
//
// LinOSS layer (B=16, N=4096, q=256) on MI355X gfx950.
// Round 10: pass fusion via linear superposition of the scan.
//   z_true(n) = P(n)10*ix + P(n)11*iz + z_local(n),  P(n) = M^(n+1)
// Pipeline (fast path, 5 kernels):
//   prep:   u -> ubP (packed-fragment bf16), W_B/W_C/W_D -> packed bf16
//   gemm1f: ubP @ WBbP^T -> fx (regs) -> scale -> LDS transpose (64KB) ->
//           in-block chunk-local scan (CHUNKS=64, CLEN=64; each 128-row
//           m-tile = exactly 2 chunks) -> lzP (packed-fragment fp32, ws)
//           + chunk end-states ex/ez
//   scan2:  compose chunk initial states ix/iz (tiny)
//   mpow:   P(n)=M^(n+1) z-row table t10/t11 [64][256] fp32 (128KB, L2)
//   gemm2f: A-frag = lzP + t10*ix + t11*iz (fp32) -> write y fp32 (once)
//           -> bf16 -> MFMA with WCbP; + ubP @ WDbP; epilogue erf-GELU ->
//           g*sigmoid(g) + u -> out0
// Packed-fragment layout (R9, validated): chunk[(tm*8+tk)*64+lane] holds
// row tm*16+(lane&15), cols tk*32+(lane>>4)*8..+7 -> all fragment loads are
// 64x16B (bf16) / 64x32B (fp32) fully coalesced.
// Old fp32-LDS-staging GEMM path retained as fallback for small ws_size.

#include <hip/hip_runtime.h>
#include <hip/hip_bf16.h>
#include <cstdint>

typedef __bf16 bf16_t;
typedef __bf16 bf16x8 __attribute__((ext_vector_type(8)));
typedef float f32x4 __attribute__((ext_vector_type(4)));

#define B_SZ 16
#define N_SZ 4096
#define Q_SZ 256
#define M_TOT (B_SZ * N_SZ) /* 65536 */
#define DT (1.0f / 4096.0f)
#define LDST 40 /* fallback-path LDS row stride in bf16 elems */
#define CHUNKS 64
#define LOG2_CLEN 6
#define CLEN (N_SZ / CHUNKS) /* 64 */
#define PF 8

// ---------------- shared helpers ----------------

// load 8 contiguous fp32, convert to bf16x8 (RNE)
__device__ __forceinline__ bf16x8 load8f(const float* p) {
  const float4 v0 = *(const float4*)p;
  const float4 v1 = *(const float4*)(p + 4);
  bf16x8 v;
  v[0] = (bf16_t)v0.x; v[1] = (bf16_t)v0.y; v[2] = (bf16_t)v0.z; v[3] = (bf16_t)v0.w;
  v[4] = (bf16_t)v1.x; v[5] = (bf16_t)v1.y; v[6] = (bf16_t)v1.z; v[7] = (bf16_t)v1.w;
  return v;
}

// packed-fragment chunk element offset of (tm, tk, lane)
__device__ __forceinline__ int pidx(int tm, int tk, int lane) {
  return ((tm * 8 + tk) * 64 + lane) * 8;
}

// single-A packed kpass: full K=256 for one wave's 64x64 tile
__device__ __forceinline__ void kpassP(const bf16_t* __restrict__ A,
                                       const bf16_t* __restrict__ Bw,
                                       int tmA, int tnB, int lane,
                                       f32x4 acc[4][4]) {
#pragma unroll
  for (int tk = 0; tk < 8; ++tk) {
    bf16x8 af[4], bv[4];
#pragma unroll
    for (int i = 0; i < 4; ++i) {
      af[i] = *(const bf16x8*)(A + pidx(tmA + i, tk, lane));
      bv[i] = *(const bf16x8*)(Bw + pidx(tnB + i, tk, lane));
    }
#pragma unroll
    for (int mi = 0; mi < 4; ++mi)
#pragma unroll
      for (int ni = 0; ni < 4; ++ni)
        acc[mi][ni] = __builtin_amdgcn_mfma_f32_16x16x32_bf16(af[mi], bv[ni],
                                                              acc[mi][ni], 0, 0, 0);
  }
}

// prep: u (65536x256 f32) -> packed bf16; WB/WC/WD (256x256 f32) -> packed bf16
__global__ __launch_bounds__(256) void prep_kernel(
    const float* __restrict__ u, const float* __restrict__ WB,
    const float* __restrict__ WC, const float* __restrict__ WD,
    bf16_t* __restrict__ ubP, bf16_t* __restrict__ WBbP,
    bf16_t* __restrict__ WCbP, bf16_t* __restrict__ WDbP) {
  const int g = blockIdx.x * 256 + threadIdx.x;
  const int UC = (M_TOT * Q_SZ) / 8; // 2,097,152 chunks
  const float* src;
  bf16_t* dst;
  int cidx;
  if (g < UC) {
    src = u; dst = ubP; cidx = g;
  } else {
    const int h = g - UC; // 0..24575
    const int w = h >> 13;
    cidx = h & 8191;
    src = (w == 0) ? WB : (w == 1) ? WC : WD;
    dst = (w == 0) ? WBbP : (w == 1) ? WCbP : WDbP;
  }
  const int lane = cidx & 63, tk = (cidx >> 6) & 7, tm = cidx >> 9;
  const int row = tm * 16 + (lane & 15);
  const int col = tk * 32 + (lane >> 4) * 8;
  *(bf16x8*)(dst + (size_t)cidx * 8) = load8f(src + (size_t)row * Q_SZ + col);
}

// ---------------- gemm1f: GEMM + in-block chunk-local scan ----------------
__global__ __launch_bounds__(256, 2) void gemm1f_kernel(
    const bf16_t* __restrict__ ubP, const bf16_t* __restrict__ WBbP,
    const float* __restrict__ a, const float* __restrict__ bB,
    float* __restrict__ ex, float* __restrict__ ez,
    float* __restrict__ lzP) {
  __shared__ float T[2][64][128]; // 64 KB: [chunk][n_local][col_local]
  const int t = threadIdx.x;
  const int bid = blockIdx.x;
  const int swz = (bid & 7) * 128 + (bid >> 3); // bijective XCD swizzle, nwg=1024
  const int m0 = (swz >> 1) * 128, n0 = (swz & 1) * 128;
  const int lane = t & 63, ln = lane & 15, quad = lane >> 4;
  const int wave = t >> 6;
  const int wm = (wave & 1) * 64, wn = (wave >> 1) * 64;
  f32x4 acc[4][4] = {};
  kpassP(ubP, WBbP, (m0 + wm) >> 4, (n0 + wn) >> 4, lane, acc);

  // scale fx = dt*s_p*(acc + bB) and deposit into LDS (chunk cc = wave&1)
  const int cc = wave & 1;
#pragma unroll
  for (int ni = 0; ni < 4; ++ni) {
    const int colL = wn + ni * 16 + ln;   // block-local col 0..127
    const int gp = n0 + colL;
    const float av = a[gp];
    const float s = 1.0f / (1.0f + DT * DT * av);
    const float sc = DT * s;
    const float bb = bB[gp];
#pragma unroll
    for (int mi = 0; mi < 4; ++mi) {
      const int nrow = mi * 16 + quad * 4; // chunk-local n
#pragma unroll
      for (int r2 = 0; r2 < 4; ++r2)
        T[cc][nrow + r2][colL] = sc * (acc[mi][ni][r2] + bb);
    }
  }
  __syncthreads();

  // chunk-local zero-init scan: thread = (chunk scc, col)
  const int scc = t >> 7, col = t & 127;
  const int pg = n0 + col;
  {
    const float av = a[pg];
    const float s = 1.0f / (1.0f + DT * DT * av);
    const float dsa = DT * s * av, dss = DT * s;
    const int mbase = m0 + scc * 64;
    const int tkp = pg >> 5, e = pg & 7;
    const int plane = (((pg >> 3) & 3) << 4); // lane = (m&15) | plane
    float x = 0.f, z = 0.f;
#pragma unroll 8
    for (int n = 0; n < 64; ++n) {
      const float f = T[scc][n][col];
      const float xn = fmaf(s, x, fmaf(-dsa, z, f));
      const float zn = fmaf(dss, x, fmaf(s, z, DT * f));
      x = xn; z = zn;
      const int m = mbase + n;
      const int tm = m >> 4;
      lzP[(size_t)(((tm * 8 + tkp) * 64 + (plane | (m & 15)))) * 8 + e] = zn;
    }
    const int chunk_g = mbase >> 6;
    ex[chunk_g * 256 + pg] = x;
    ez[chunk_g * 256 + pg] = z;
  }
}

// scan2: compose chunk initial states (state BEFORE each chunk)
__global__ __launch_bounds__(256) void scan2_kernel(
    const float* __restrict__ a, const float* __restrict__ ex,
    const float* __restrict__ ez, float* __restrict__ ix, float* __restrict__ iz) {
  const int g = blockIdx.x * 256 + threadIdx.x; // 0..4095
  const int p = g & 255, b = g >> 8;
  const float av = a[p];
  const float s = 1.0f / (1.0f + DT * DT * av);
  float m00 = s, m01 = -DT * s * av, m10 = DT * s, m11 = s;
#pragma unroll
  for (int i = 0; i < LOG2_CLEN; ++i) { // M^(2^LOG2_CLEN) = M^CLEN
    const float a00 = fmaf(m00, m00, m01 * m10);
    const float a01 = m01 * (m00 + m11);
    const float a10 = m10 * (m00 + m11);
    const float a11 = fmaf(m11, m11, m01 * m10);
    m00 = a00; m01 = a01; m10 = a10; m11 = a11;
  }
  float x = 0.f, z = 0.f;
  for (int c = 0; c < CHUNKS; ++c) {
    const size_t idx = ((size_t)b * CHUNKS + c) * Q_SZ + p;
    ix[idx] = x; iz[idx] = z;
    const float xn = fmaf(m00, x, fmaf(m01, z, ex[idx]));
    const float zn = fmaf(m10, x, fmaf(m11, z, ez[idx]));
    x = xn; z = zn;
  }
}

// mpow: z-row of P(n)=M^(n+1): t10[n][p], t11[n][p] for n=0..63
__global__ __launch_bounds__(256) void mpow_kernel(
    const float* __restrict__ a, float* __restrict__ t10,
    float* __restrict__ t11) {
  const int p = threadIdx.x;
  const float av = a[p];
  const float s = 1.0f / (1.0f + DT * DT * av);
  const float m00 = s, m01 = -DT * s * av, m10 = DT * s, m11 = s;
  float p00 = m00, p01 = m01, p10 = m10, p11 = m11; // P(0) = M
  for (int n = 0; n < 64; ++n) {
    t10[n * 256 + p] = p10;
    t11[n * 256 + p] = p11;
    const float q00 = fmaf(m00, p00, m01 * p10);
    const float q01 = fmaf(m00, p01, m01 * p11);
    const float q10 = fmaf(m10, p00, m11 * p10);
    const float q11 = fmaf(m10, p01, m11 * p11);
    p00 = q00; p01 = q01; p10 = q10; p11 = q11;
  }
}

// gemm2f: y = lzP + corr (write y fp32 once); x = y@WC^T + u@WD^T + biases;
// g = gelu_erf(x); out0 = g*sigmoid(g) + u
__global__ __launch_bounds__(256, 2) void gemm2f_kernel(
    const float* __restrict__ lzP, const bf16_t* __restrict__ WCbP,
    const bf16_t* __restrict__ ubP, const bf16_t* __restrict__ WDbP,
    const float* __restrict__ ix, const float* __restrict__ iz,
    const float* __restrict__ t10, const float* __restrict__ t11,
    const float* __restrict__ u, const float* __restrict__ bC,
    const float* __restrict__ bD, float* __restrict__ yout,
    float* __restrict__ out0) {
  const int t = threadIdx.x;
  const int bid = blockIdx.x;
  const int swz = (bid & 7) * 128 + (bid >> 3);
  const int m0 = (swz >> 1) * 128, n0 = (swz & 1) * 128;
  const int lane = t & 63, ln = lane & 15, quad = lane >> 4;
  const int wave = t >> 6;
  const int wm = (wave & 1) * 64, wn = (wave >> 1) * 64;
  const int tmA = (m0 + wm) >> 4, tnB = (n0 + wn) >> 4;
  const bool wY = (n0 == 0) && (wn == 0); // write y exactly once
  f32x4 acc[4][4] = {};
#pragma unroll
  for (int tk = 0; tk < 8; ++tk) {
    bf16x8 af[4], bv[4], a2[4], b2[4];
#pragma unroll
    for (int i = 0; i < 4; ++i) {
      const float* lp = lzP + (size_t)(((tmA + i) * 8 + tk) * 64 + lane) * 8;
      const f32x4 l0 = *(const f32x4*)lp;
      const f32x4 l1 = *(const f32x4*)(lp + 4);
      const int m = (tmA + i) * 16 + ln;
      const int nloc = m & 63, cg = m >> 6;
      const int p0 = tk * 32 + quad * 8;
      const f32x4 tA0 = *(const f32x4*)(t10 + nloc * 256 + p0);
      const f32x4 tA1 = *(const f32x4*)(t10 + nloc * 256 + p0 + 4);
      const f32x4 tB0 = *(const f32x4*)(t11 + nloc * 256 + p0);
      const f32x4 tB1 = *(const f32x4*)(t11 + nloc * 256 + p0 + 4);
      const f32x4 X0 = *(const f32x4*)(ix + cg * 256 + p0);
      const f32x4 X1 = *(const f32x4*)(ix + cg * 256 + p0 + 4);
      const f32x4 Z0 = *(const f32x4*)(iz + cg * 256 + p0);
      const f32x4 Z1 = *(const f32x4*)(iz + cg * 256 + p0 + 4);
      f32x4 y0, y1;
#pragma unroll
      for (int e = 0; e < 4; ++e) {
        y0[e] = fmaf(tA0[e], X0[e], fmaf(tB0[e], Z0[e], l0[e]));
        y1[e] = fmaf(tA1[e], X1[e], fmaf(tB1[e], Z1[e], l1[e]));
      }
      if (wY) {
        *(f32x4*)(yout + (size_t)m * Q_SZ + p0) = y0;
        *(f32x4*)(yout + (size_t)m * Q_SZ + p0 + 4) = y1;
      }
      bf16x8 av_;
#pragma unroll
      for (int e = 0; e < 4; ++e) {
        av_[e] = (bf16_t)y0[e];
        av_[e + 4] = (bf16_t)y1[e];
      }
      af[i] = av_;
      a2[i] = *(const bf16x8*)(ubP + pidx(tmA + i, tk, lane));
      bv[i] = *(const bf16x8*)(WCbP + pidx(tnB + i, tk, lane));
      b2[i] = *(const bf16x8*)(WDbP + pidx(tnB + i, tk, lane));
    }
#pragma unroll
    for (int mi = 0; mi < 4; ++mi)
#pragma unroll
      for (int ni = 0; ni < 4; ++ni)
        acc[mi][ni] = __builtin_amdgcn_mfma_f32_16x16x32_bf16(af[mi], bv[ni],
                                                              acc[mi][ni], 0, 0, 0);
#pragma unroll
    for (int mi = 0; mi < 4; ++mi)
#pragma unroll
      for (int ni = 0; ni < 4; ++ni)
        acc[mi][ni] = __builtin_amdgcn_mfma_f32_16x16x32_bf16(a2[mi], b2[ni],
                                                              acc[mi][ni], 0, 0, 0);
  }
#pragma unroll
  for (int ni = 0; ni < 4; ++ni) {
    const int gp = n0 + wn + ni * 16 + ln;
    const float bias = bC[gp] + bD[gp];
#pragma unroll
    for (int mi = 0; mi < 4; ++mi) {
      const int gm = m0 + wm + mi * 16 + quad * 4;
#pragma unroll
      for (int r2 = 0; r2 < 4; ++r2) {
        const float x = acc[mi][ni][r2] + bias;
        const float g = 0.5f * x * (1.0f + erff(x * 0.70710678118654752f));
        const float sg = 1.0f / (1.0f + __expf(-g));
        const float uu = u[(size_t)(gm + r2) * Q_SZ + gp];
        out0[(size_t)(gm + r2) * Q_SZ + gp] = fmaf(g, sg, uu);
      }
    }
  }
}

// ---------------- fallback path (fp32 LDS GEMMs + 3-phase scan) ----------------

__device__ __forceinline__ void kloop(const float* __restrict__ Ap,
                                      const float* __restrict__ Bp,
                                      int m0, int n0, int t,
                                      bf16_t* As, bf16_t* Bs, f32x4 acc[4][4]) {
  const int r = t >> 2, cc = t & 3;
  const int lane = t & 63, ln = lane & 15, quad = lane >> 4;
  const int wave = t >> 6;
  const int wm = (wave & 1) * 64, wn = (wave >> 1) * 64;

  for (int k0 = 0; k0 < Q_SZ; k0 += 32) {
#pragma unroll
    for (int i = 0; i < 2; ++i) {
      const int row = r + i * 64;
      const int col = k0 + cc * 8;
      *(bf16x8*)(As + row * LDST + cc * 8) =
          load8f(Ap + (size_t)(m0 + row) * Q_SZ + col);
      *(bf16x8*)(Bs + row * LDST + cc * 8) =
          load8f(Bp + (size_t)(n0 + row) * Q_SZ + col);
    }
    __syncthreads();
    bf16x8 af[4], bv[4];
#pragma unroll
    for (int mi = 0; mi < 4; ++mi) {
      af[mi] = *(const bf16x8*)(As + (wm + mi * 16 + ln) * LDST + quad * 8);
      bv[mi] = *(const bf16x8*)(Bs + (wn + mi * 16 + ln) * LDST + quad * 8);
    }
#pragma unroll
    for (int mi = 0; mi < 4; ++mi)
#pragma unroll
      for (int ni = 0; ni < 4; ++ni)
        acc[mi][ni] = __builtin_amdgcn_mfma_f32_16x16x32_bf16(af[mi], bv[ni],
                                                              acc[mi][ni], 0, 0, 0);
    __syncthreads();
  }
}

__global__ __launch_bounds__(256) void gemm1_kernel(
    const float* __restrict__ u, const float* __restrict__ WB,
    const float* __restrict__ a, const float* __restrict__ bB,
    float* __restrict__ fx) {
  __shared__ __align__(16) bf16_t As[128 * LDST];
  __shared__ __align__(16) bf16_t Bs[128 * LDST];
  const int t = threadIdx.x;
  const int m0 = blockIdx.x * 128, n0 = blockIdx.y * 128;
  f32x4 acc[4][4] = {};
  kloop(u, WB, m0, n0, t, As, Bs, acc);

  const int lane = t & 63, ln = lane & 15, quad = lane >> 4;
  const int wave = t >> 6;
  const int wm = (wave & 1) * 64, wn = (wave >> 1) * 64;
#pragma unroll
  for (int ni = 0; ni < 4; ++ni) {
    const int gp = n0 + wn + ni * 16 + ln;
    const float av = a[gp];
    const float s = 1.0f / (1.0f + DT * DT * av);
    const float sc = DT * s;
    const float bb = bB[gp];
#pragma unroll
    for (int mi = 0; mi < 4; ++mi) {
      const int gm = m0 + wm + mi * 16 + quad * 4;
#pragma unroll
      for (int r2 = 0; r2 < 4; ++r2)
        fx[(size_t)(gm + r2) * Q_SZ + gp] = sc * (acc[mi][ni][r2] + bb);
    }
  }
}

__global__ __launch_bounds__(256) void gemm2_kernel(
    const float* __restrict__ y, const float* __restrict__ WC,
    const float* __restrict__ u, const float* __restrict__ WD,
    const float* __restrict__ bC, const float* __restrict__ bD,
    float* __restrict__ out0) {
  __shared__ __align__(16) bf16_t As[128 * LDST];
  __shared__ __align__(16) bf16_t Bs[128 * LDST];
  const int t = threadIdx.x;
  const int m0 = blockIdx.x * 128, n0 = blockIdx.y * 128;
  f32x4 acc[4][4] = {};
  kloop(y, WC, m0, n0, t, As, Bs, acc);
  kloop(u, WD, m0, n0, t, As, Bs, acc);

  const int lane = t & 63, ln = lane & 15, quad = lane >> 4;
  const int wave = t >> 6;
  const int wm = (wave & 1) * 64, wn = (wave >> 1) * 64;
#pragma unroll
  for (int ni = 0; ni < 4; ++ni) {
    const int gp = n0 + wn + ni * 16 + ln;
    const float bias = bC[gp] + bD[gp];
#pragma unroll
    for (int mi = 0; mi < 4; ++mi) {
      const int gm = m0 + wm + mi * 16 + quad * 4;
#pragma unroll
      for (int r2 = 0; r2 < 4; ++r2) {
        const float x = acc[mi][ni][r2] + bias;
        const float g = 0.5f * x * (1.0f + erff(x * 0.70710678118654752f));
        const float sg = 1.0f / (1.0f + __expf(-g));
        const float uu = u[(size_t)(gm + r2) * Q_SZ + gp];
        out0[(size_t)(gm + r2) * Q_SZ + gp] = fmaf(g, sg, uu);
      }
    }
  }
}

__global__ __launch_bounds__(256) void scan1_kernel(
    const float* __restrict__ fx, const float* __restrict__ a,
    float* __restrict__ ex, float* __restrict__ ez) {
  const int g = blockIdx.x * 256 + threadIdx.x;
  const int p = g & 255, c = (g >> 8) & (CHUNKS - 1), b = g >> 14;
  const float av = a[p];
  const float s = 1.0f / (1.0f + DT * DT * av);
  const float dsa = DT * s * av, dss = DT * s;
  float x = 0.f, z = 0.f;
  const float* fp = fx + ((size_t)b * N_SZ + c * CLEN) * Q_SZ + p;
  for (int n = 0; n < CLEN; ++n) {
    const float f = fp[(size_t)n * Q_SZ];
    const float xn = fmaf(s, x, fmaf(-dsa, z, f));
    const float zn = fmaf(dss, x, fmaf(s, z, DT * f));
    x = xn; z = zn;
  }
  ex[g] = x; ez[g] = z;
}

__global__ __launch_bounds__(256) void scan3_kernel(
    const float* __restrict__ a, const float* __restrict__ ix,
    const float* __restrict__ iz, float* __restrict__ yf) {
  const int g = blockIdx.x * 256 + threadIdx.x;
  const int p = g & 255, c = (g >> 8) & (CHUNKS - 1), b = g >> 14;
  const float av = a[p];
  const float s = 1.0f / (1.0f + DT * DT * av);
  const float dsa = DT * s * av, dss = DT * s;
  float x = ix[g], z = iz[g];
  float* yp = yf + ((size_t)b * N_SZ + c * CLEN) * Q_SZ + p;
  for (int n = 0; n < CLEN; ++n) {
    const float f = yp[(size_t)n * Q_SZ];
    const float xn = fmaf(s, x, fmaf(-dsa, z, f));
    const float zn = fmaf(dss, x, fmaf(s, z, DT * f));
    x = xn; z = zn;
    yp[(size_t)n * Q_SZ] = zn;
  }
}

__global__ __launch_bounds__(256) void scan_mono_kernel(
    const float* __restrict__ a, float* __restrict__ yf) {
  const int g = blockIdx.x * 256 + threadIdx.x;
  const int p = g & 255, b = g >> 8;
  const float av = a[p];
  const float s = 1.0f / (1.0f + DT * DT * av);
  const float dsa = DT * s * av, dss = DT * s;
  float x = 0.f, z = 0.f;
  float* yp = yf + (size_t)b * N_SZ * Q_SZ + p;
  for (int n = 0; n < N_SZ; ++n) {
    const float f = yp[(size_t)n * Q_SZ];
    const float xn = fmaf(s, x, fmaf(-dsa, z, f));
    const float zn = fmaf(dss, x, fmaf(s, z, DT * f));
    x = xn; z = zn;
    yp[(size_t)n * Q_SZ] = zn;
  }
}

// ---------------- launcher ----------------

extern "C" void kernel_launch(void* const* d_in, const int* in_sizes, int n_in,
                              void* d_out, int out_size, void* d_ws, size_t ws_size,
                              hipStream_t stream) {
  const float* u  = (const float*)d_in[0];
  const float* a  = (const float*)d_in[1];
  const float* WB = (const float*)d_in[2];
  const float* bB = (const float*)d_in[3];
  const float* WC = (const float*)d_in[4];
  const float* bC = (const float*)d_in[5];
  const float* WD = (const float*)d_in[6];
  const float* bD = (const float*)d_in[7];

  float* out0 = (float*)d_out;                // first 16.7M fp32: out
  float* yreg = out0 + (size_t)M_TOT * Q_SZ;  // second 16.7M fp32: y

  const size_t UB_ELEMS = (size_t)M_TOT * Q_SZ;  // 16,777,216
  const size_t W_ELEMS = (size_t)Q_SZ * Q_SZ;    // 65,536
  const size_t ST_ELEMS = (size_t)B_SZ * CHUNKS * Q_SZ; // 262,144
  const size_t need_full =
      UB_ELEMS * sizeof(bf16_t) + 3 * W_ELEMS * sizeof(bf16_t) +
      UB_ELEMS * sizeof(float) + 4 * ST_ELEMS * sizeof(float) +
      2 * 64 * 256 * sizeof(float); // ~105.2 MB
  const size_t state_bytes = 4 * ST_ELEMS * sizeof(float); // 4 MiB

  if (ws_size >= need_full) {
    bf16_t* ubP  = (bf16_t*)d_ws;
    bf16_t* WBbP = ubP + UB_ELEMS;
    bf16_t* WCbP = WBbP + W_ELEMS;
    bf16_t* WDbP = WCbP + W_ELEMS;
    float* lzP = (float*)(WDbP + W_ELEMS);
    float* ex = lzP + UB_ELEMS;
    float* ez = ex + ST_ELEMS;
    float* ix = ez + ST_ELEMS;
    float* iz = ix + ST_ELEMS;
    float* t10 = iz + ST_ELEMS;
    float* t11 = t10 + 64 * 256;

    prep_kernel<<<8288, 256, 0, stream>>>(u, WB, WC, WD, ubP, WBbP, WCbP, WDbP);
    gemm1f_kernel<<<1024, 256, 0, stream>>>(ubP, WBbP, a, bB, ex, ez, lzP);
    scan2_kernel<<<16, 256, 0, stream>>>(a, ex, ez, ix, iz);
    mpow_kernel<<<1, 256, 0, stream>>>(a, t10, t11);
    gemm2f_kernel<<<1024, 256, 0, stream>>>(lzP, WCbP, ubP, WDbP, ix, iz,
                                            t10, t11, u, bC, bD, yreg, out0);
  } else {
    dim3 gg(M_TOT / 128, Q_SZ / 128);
    gemm1_kernel<<<gg, 256, 0, stream>>>(u, WB, a, bB, yreg);
    if (ws_size >= state_bytes) {
      float* ex = (float*)d_ws;
      float* ez = ex + ST_ELEMS;
      float* ix = ez + ST_ELEMS;
      float* iz = ix + ST_ELEMS;
      scan1_kernel<<<1024, 256, 0, stream>>>(yreg, a, ex, ez);
      scan2_kernel<<<16, 256, 0, stream>>>(a, ex, ez, ix, iz);
      scan3_kernel<<<1024, 256, 0, stream>>>(a, ix, iz, yreg);
    } else {
      scan_mono_kernel<<<16, 256, 0, stream>>>(a, yreg);
    }
    gemm2_kernel<<<gg, 256, 0, stream>>>(yreg, WC, u, WD, bC, bD, out0);
  }
}

// Round 5
// 325.008 us; speedup vs baseline: 1.2153x; 1.2153x over previous
//
// LinOSS layer (B=16, N=4096, q=256) on MI355X gfx950.
// Round 11: superposition fusion, placed correctly this time.
//   z_true(n) = P(n)10*ix + P(n)11*iz + z_local(n),  P(n) = M^(n+1)
// R10 lesson: applying the correction inside gemm2's fragment producer is
// per-FRAGMENT recomputation (8 extra loads + 16 FMA each, VGPR 108,
// divergent y-writes) -> 170us. Correction belongs in a streaming
// elementwise pass (once per ELEMENT).
// Fast path (6 kernels):
//   prep:   u -> ubP (packed-fragment bf16), W_B/W_C/W_D -> packed bf16
//   gemm1f: ubP @ WBbP^T (packed, validated R9 body) -> scale -> LDS
//           transpose (row stride 133, <=2-way banks) -> 64-step chunk-local
//           scan (zero init) -> lz ROW-MAJOR fp32 into y-region (coalesced)
//           + chunk end-states ex/ez
//   scan2:  compose chunk initial states ix/iz (tiny)
//   mpow:   P(n) z-row table t10/t11 [64][256] fp32 (64KB, L2-resident)
//   fix3:   y[m,p] = t10[m&63,p]*ix[m>>6,p] + t11[m&63,p]*iz[m>>6,p] + lz
//           IN PLACE over y-region; also emits ybP (packed bf16) for gemm2p.
//           Pure streaming: 160MB -> ~25us.
//   gemm2p: ybP@WCbP^T + ubP@WDbP^T (R9 verbatim) -> erf-GELU ->
//           g*sigmoid(g) + u -> out0
// Packed-fragment layout (R9, validated): chunk[(tm*8+tk)*64+lane] holds
// row tm*16+(lane&15), cols tk*32+(lane>>4)*8..+7.
// Old fp32-LDS-staging GEMM path retained as fallback for small ws_size.

#include <hip/hip_runtime.h>
#include <hip/hip_bf16.h>
#include <cstdint>

typedef __bf16 bf16_t;
typedef __bf16 bf16x8 __attribute__((ext_vector_type(8)));
typedef float f32x4 __attribute__((ext_vector_type(4)));

#define B_SZ 16
#define N_SZ 4096
#define Q_SZ 256
#define M_TOT (B_SZ * N_SZ) /* 65536 */
#define DT (1.0f / 4096.0f)
#define LDST 40 /* fallback-path LDS row stride in bf16 elems */
#define CHUNKS 64
#define LOG2_CLEN 6
#define CLEN (N_SZ / CHUNKS) /* 64 */
#define TPAD 133 /* gemm1f LDS transpose row stride (floats) */

// ---------------- shared helpers ----------------

// load 8 contiguous fp32, convert to bf16x8 (RNE)
__device__ __forceinline__ bf16x8 load8f(const float* p) {
  const float4 v0 = *(const float4*)p;
  const float4 v1 = *(const float4*)(p + 4);
  bf16x8 v;
  v[0] = (bf16_t)v0.x; v[1] = (bf16_t)v0.y; v[2] = (bf16_t)v0.z; v[3] = (bf16_t)v0.w;
  v[4] = (bf16_t)v1.x; v[5] = (bf16_t)v1.y; v[6] = (bf16_t)v1.z; v[7] = (bf16_t)v1.w;
  return v;
}

// packed-fragment chunk element offset of (tm, tk, lane)
__device__ __forceinline__ int pidx(int tm, int tk, int lane) {
  return ((tm * 8 + tk) * 64 + lane) * 8;
}

// single-A packed kpass: full K=256 for one wave's 64x64 tile
__device__ __forceinline__ void kpassP(const bf16_t* __restrict__ A,
                                       const bf16_t* __restrict__ Bw,
                                       int tmA, int tnB, int lane,
                                       f32x4 acc[4][4]) {
#pragma unroll
  for (int tk = 0; tk < 8; ++tk) {
    bf16x8 af[4], bv[4];
#pragma unroll
    for (int i = 0; i < 4; ++i) {
      af[i] = *(const bf16x8*)(A + pidx(tmA + i, tk, lane));
      bv[i] = *(const bf16x8*)(Bw + pidx(tnB + i, tk, lane));
    }
#pragma unroll
    for (int mi = 0; mi < 4; ++mi)
#pragma unroll
      for (int ni = 0; ni < 4; ++ni)
        acc[mi][ni] = __builtin_amdgcn_mfma_f32_16x16x32_bf16(af[mi], bv[ni],
                                                              acc[mi][ni], 0, 0, 0);
  }
}

// prep: u (65536x256 f32) -> packed bf16; WB/WC/WD (256x256 f32) -> packed bf16
__global__ __launch_bounds__(256) void prep_kernel(
    const float* __restrict__ u, const float* __restrict__ WB,
    const float* __restrict__ WC, const float* __restrict__ WD,
    bf16_t* __restrict__ ubP, bf16_t* __restrict__ WBbP,
    bf16_t* __restrict__ WCbP, bf16_t* __restrict__ WDbP) {
  const int g = blockIdx.x * 256 + threadIdx.x;
  const int UC = (M_TOT * Q_SZ) / 8; // 2,097,152 chunks
  const float* src;
  bf16_t* dst;
  int cidx;
  if (g < UC) {
    src = u; dst = ubP; cidx = g;
  } else {
    const int h = g - UC; // 0..24575
    const int w = h >> 13;
    cidx = h & 8191;
    src = (w == 0) ? WB : (w == 1) ? WC : WD;
    dst = (w == 0) ? WBbP : (w == 1) ? WCbP : WDbP;
  }
  const int lane = cidx & 63, tk = (cidx >> 6) & 7, tm = cidx >> 9;
  const int row = tm * 16 + (lane & 15);
  const int col = tk * 32 + (lane >> 4) * 8;
  *(bf16x8*)(dst + (size_t)cidx * 8) = load8f(src + (size_t)row * Q_SZ + col);
}

// ---------------- gemm1f: GEMM + in-block chunk-local scan ----------------
__global__ __launch_bounds__(256, 2) void gemm1f_kernel(
    const bf16_t* __restrict__ ubP, const bf16_t* __restrict__ WBbP,
    const float* __restrict__ a, const float* __restrict__ bB,
    float* __restrict__ ex, float* __restrict__ ez,
    float* __restrict__ lz) {
  __shared__ float T[2][64][TPAD]; // ~66.5 KB: [chunk][n_local][col_local]
  const int t = threadIdx.x;
  const int bid = blockIdx.x;
  const int swz = (bid & 7) * 128 + (bid >> 3); // bijective XCD swizzle, nwg=1024
  const int m0 = (swz >> 1) * 128, n0 = (swz & 1) * 128;
  const int lane = t & 63, ln = lane & 15, quad = lane >> 4;
  const int wave = t >> 6;
  const int wm = (wave & 1) * 64, wn = (wave >> 1) * 64;
  f32x4 acc[4][4] = {};
  kpassP(ubP, WBbP, (m0 + wm) >> 4, (n0 + wn) >> 4, lane, acc);

  // scale fx = dt*s_p*(acc + bB) and deposit into LDS (chunk cc = wave&1)
  const int cc = wave & 1;
#pragma unroll
  for (int ni = 0; ni < 4; ++ni) {
    const int colL = wn + ni * 16 + ln;   // block-local col 0..127
    const int gp = n0 + colL;
    const float av = a[gp];
    const float s = 1.0f / (1.0f + DT * DT * av);
    const float sc = DT * s;
    const float bb = bB[gp];
#pragma unroll
    for (int mi = 0; mi < 4; ++mi) {
      const int nrow = mi * 16 + quad * 4; // chunk-local n
#pragma unroll
      for (int r2 = 0; r2 < 4; ++r2)
        T[cc][nrow + r2][colL] = sc * (acc[mi][ni][r2] + bb);
    }
  }
  __syncthreads();

  // chunk-local zero-init scan: thread = (chunk scc, col); coalesced lz write
  const int scc = t >> 7, col = t & 127;
  const int pg = n0 + col;
  {
    const float av = a[pg];
    const float s = 1.0f / (1.0f + DT * DT * av);
    const float dsa = DT * s * av, dss = DT * s;
    const int mbase = m0 + scc * 64;
    float x = 0.f, z = 0.f;
    float* lp = lz + (size_t)mbase * Q_SZ + pg;
#pragma unroll 8
    for (int n = 0; n < 64; ++n) {
      const float f = T[scc][n][col];
      const float xn = fmaf(s, x, fmaf(-dsa, z, f));
      const float zn = fmaf(dss, x, fmaf(s, z, DT * f));
      x = xn; z = zn;
      lp[(size_t)n * Q_SZ] = zn;
    }
    const int chunk_g = mbase >> 6;
    ex[chunk_g * 256 + pg] = x;
    ez[chunk_g * 256 + pg] = z;
  }
}

// scan2: compose chunk initial states (state BEFORE each chunk)
__global__ __launch_bounds__(256) void scan2_kernel(
    const float* __restrict__ a, const float* __restrict__ ex,
    const float* __restrict__ ez, float* __restrict__ ix, float* __restrict__ iz) {
  const int g = blockIdx.x * 256 + threadIdx.x; // 0..4095
  const int p = g & 255, b = g >> 8;
  const float av = a[p];
  const float s = 1.0f / (1.0f + DT * DT * av);
  float m00 = s, m01 = -DT * s * av, m10 = DT * s, m11 = s;
#pragma unroll
  for (int i = 0; i < LOG2_CLEN; ++i) { // M^(2^LOG2_CLEN) = M^CLEN
    const float a00 = fmaf(m00, m00, m01 * m10);
    const float a01 = m01 * (m00 + m11);
    const float a10 = m10 * (m00 + m11);
    const float a11 = fmaf(m11, m11, m01 * m10);
    m00 = a00; m01 = a01; m10 = a10; m11 = a11;
  }
  float x = 0.f, z = 0.f;
  for (int c = 0; c < CHUNKS; ++c) {
    const size_t idx = ((size_t)b * CHUNKS + c) * Q_SZ + p;
    ix[idx] = x; iz[idx] = z;
    const float xn = fmaf(m00, x, fmaf(m01, z, ex[idx]));
    const float zn = fmaf(m10, x, fmaf(m11, z, ez[idx]));
    x = xn; z = zn;
  }
}

// mpow: z-row of P(n)=M^(n+1): t10[n][p], t11[n][p] for n=0..63
__global__ __launch_bounds__(256) void mpow_kernel(
    const float* __restrict__ a, float* __restrict__ t10,
    float* __restrict__ t11) {
  const int p = threadIdx.x;
  const float av = a[p];
  const float s = 1.0f / (1.0f + DT * DT * av);
  const float m00 = s, m01 = -DT * s * av, m10 = DT * s, m11 = s;
  float p00 = m00, p01 = m01, p10 = m10, p11 = m11; // P(0) = M
  for (int n = 0; n < 64; ++n) {
    t10[n * 256 + p] = p10;
    t11[n * 256 + p] = p11;
    const float q00 = fmaf(m00, p00, m01 * p10);
    const float q01 = fmaf(m00, p01, m01 * p11);
    const float q10 = fmaf(m10, p00, m11 * p10);
    const float q11 = fmaf(m10, p01, m11 * p11);
    p00 = q00; p01 = q01; p10 = q10; p11 = q11;
  }
}

// fix3: y = corr + lz IN PLACE (row-major, coalesced); also emit packed ybP.
// thread g: row m = g>>5, cols p0..p0+7 with p0 = (g&31)*8
__global__ __launch_bounds__(256) void fix3_kernel(
    const float* __restrict__ ix, const float* __restrict__ iz,
    const float* __restrict__ t10, const float* __restrict__ t11,
    float* __restrict__ y, bf16_t* __restrict__ ybP) {
  const int g = blockIdx.x * 256 + threadIdx.x; // 0..2,097,151
  const int m = g >> 5, p0 = (g & 31) * 8;
  const int nloc = m & 63, cg = m >> 6;
  float* yp = y + (size_t)m * Q_SZ + p0;
  const f32x4 l0 = *(const f32x4*)yp;
  const f32x4 l1 = *(const f32x4*)(yp + 4);
  const f32x4 tA0 = *(const f32x4*)(t10 + nloc * 256 + p0);
  const f32x4 tA1 = *(const f32x4*)(t10 + nloc * 256 + p0 + 4);
  const f32x4 tB0 = *(const f32x4*)(t11 + nloc * 256 + p0);
  const f32x4 tB1 = *(const f32x4*)(t11 + nloc * 256 + p0 + 4);
  const f32x4 X0 = *(const f32x4*)(ix + cg * 256 + p0);
  const f32x4 X1 = *(const f32x4*)(ix + cg * 256 + p0 + 4);
  const f32x4 Z0 = *(const f32x4*)(iz + cg * 256 + p0);
  const f32x4 Z1 = *(const f32x4*)(iz + cg * 256 + p0 + 4);
  f32x4 y0, y1;
#pragma unroll
  for (int e = 0; e < 4; ++e) {
    y0[e] = fmaf(tA0[e], X0[e], fmaf(tB0[e], Z0[e], l0[e]));
    y1[e] = fmaf(tA1[e], X1[e], fmaf(tB1[e], Z1[e], l1[e]));
  }
  *(f32x4*)yp = y0;
  *(f32x4*)(yp + 4) = y1;
  bf16x8 v;
#pragma unroll
  for (int e = 0; e < 4; ++e) {
    v[e] = (bf16_t)y0[e];
    v[e + 4] = (bf16_t)y1[e];
  }
  const int chunk = ((m >> 4) * 8 + (p0 >> 5)) * 64 +
                    ((((p0 >> 3) & 3) << 4) | (m & 15));
  *(bf16x8*)(ybP + (size_t)chunk * 8) = v;
}

// gemm2p (R9 verbatim): x = y@WC^T + u@WD^T + biases; g = gelu_erf(x);
// out0 = g*sigmoid(g) + u
__global__ __launch_bounds__(256, 2) void gemm2p_kernel(
    const bf16_t* __restrict__ ybP, const bf16_t* __restrict__ WCbP,
    const bf16_t* __restrict__ ubP, const bf16_t* __restrict__ WDbP,
    const float* __restrict__ u, const float* __restrict__ bC,
    const float* __restrict__ bD, float* __restrict__ out0) {
  const int t = threadIdx.x;
  const int bid = blockIdx.x;
  const int swz = (bid & 7) * 128 + (bid >> 3);
  const int m0 = (swz >> 1) * 128, n0 = (swz & 1) * 128;
  const int lane = t & 63, ln = lane & 15, quad = lane >> 4;
  const int wave = t >> 6;
  const int wm = (wave & 1) * 64, wn = (wave >> 1) * 64;
  const int tmA = (m0 + wm) >> 4, tnB = (n0 + wn) >> 4;
  f32x4 acc[4][4] = {};
#pragma unroll
  for (int tk = 0; tk < 8; ++tk) {
    bf16x8 a1[4], b1[4], a2[4], b2[4];
#pragma unroll
    for (int i = 0; i < 4; ++i) {
      a1[i] = *(const bf16x8*)(ybP + pidx(tmA + i, tk, lane));
      b1[i] = *(const bf16x8*)(WCbP + pidx(tnB + i, tk, lane));
      a2[i] = *(const bf16x8*)(ubP + pidx(tmA + i, tk, lane));
      b2[i] = *(const bf16x8*)(WDbP + pidx(tnB + i, tk, lane));
    }
#pragma unroll
    for (int mi = 0; mi < 4; ++mi)
#pragma unroll
      for (int ni = 0; ni < 4; ++ni)
        acc[mi][ni] = __builtin_amdgcn_mfma_f32_16x16x32_bf16(a1[mi], b1[ni],
                                                              acc[mi][ni], 0, 0, 0);
#pragma unroll
    for (int mi = 0; mi < 4; ++mi)
#pragma unroll
      for (int ni = 0; ni < 4; ++ni)
        acc[mi][ni] = __builtin_amdgcn_mfma_f32_16x16x32_bf16(a2[mi], b2[ni],
                                                              acc[mi][ni], 0, 0, 0);
  }
#pragma unroll
  for (int ni = 0; ni < 4; ++ni) {
    const int gp = n0 + wn + ni * 16 + ln;
    const float bias = bC[gp] + bD[gp];
#pragma unroll
    for (int mi = 0; mi < 4; ++mi) {
      const int gm = m0 + wm + mi * 16 + quad * 4;
#pragma unroll
      for (int r2 = 0; r2 < 4; ++r2) {
        const float x = acc[mi][ni][r2] + bias;
        const float g = 0.5f * x * (1.0f + erff(x * 0.70710678118654752f));
        const float sg = 1.0f / (1.0f + __expf(-g));
        const float uu = u[(size_t)(gm + r2) * Q_SZ + gp];
        out0[(size_t)(gm + r2) * Q_SZ + gp] = fmaf(g, sg, uu);
      }
    }
  }
}

// ---------------- fallback path (fp32 LDS GEMMs + 3-phase scan) ----------------

__device__ __forceinline__ void kloop(const float* __restrict__ Ap,
                                      const float* __restrict__ Bp,
                                      int m0, int n0, int t,
                                      bf16_t* As, bf16_t* Bs, f32x4 acc[4][4]) {
  const int r = t >> 2, cc = t & 3;
  const int lane = t & 63, ln = lane & 15, quad = lane >> 4;
  const int wave = t >> 6;
  const int wm = (wave & 1) * 64, wn = (wave >> 1) * 64;

  for (int k0 = 0; k0 < Q_SZ; k0 += 32) {
#pragma unroll
    for (int i = 0; i < 2; ++i) {
      const int row = r + i * 64;
      const int col = k0 + cc * 8;
      *(bf16x8*)(As + row * LDST + cc * 8) =
          load8f(Ap + (size_t)(m0 + row) * Q_SZ + col);
      *(bf16x8*)(Bs + row * LDST + cc * 8) =
          load8f(Bp + (size_t)(n0 + row) * Q_SZ + col);
    }
    __syncthreads();
    bf16x8 af[4], bv[4];
#pragma unroll
    for (int mi = 0; mi < 4; ++mi) {
      af[mi] = *(const bf16x8*)(As + (wm + mi * 16 + ln) * LDST + quad * 8);
      bv[mi] = *(const bf16x8*)(Bs + (wn + mi * 16 + ln) * LDST + quad * 8);
    }
#pragma unroll
    for (int mi = 0; mi < 4; ++mi)
#pragma unroll
      for (int ni = 0; ni < 4; ++ni)
        acc[mi][ni] = __builtin_amdgcn_mfma_f32_16x16x32_bf16(af[mi], bv[ni],
                                                              acc[mi][ni], 0, 0, 0);
    __syncthreads();
  }
}

__global__ __launch_bounds__(256) void gemm1_kernel(
    const float* __restrict__ u, const float* __restrict__ WB,
    const float* __restrict__ a, const float* __restrict__ bB,
    float* __restrict__ fx) {
  __shared__ __align__(16) bf16_t As[128 * LDST];
  __shared__ __align__(16) bf16_t Bs[128 * LDST];
  const int t = threadIdx.x;
  const int m0 = blockIdx.x * 128, n0 = blockIdx.y * 128;
  f32x4 acc[4][4] = {};
  kloop(u, WB, m0, n0, t, As, Bs, acc);

  const int lane = t & 63, ln = lane & 15, quad = lane >> 4;
  const int wave = t >> 6;
  const int wm = (wave & 1) * 64, wn = (wave >> 1) * 64;
#pragma unroll
  for (int ni = 0; ni < 4; ++ni) {
    const int gp = n0 + wn + ni * 16 + ln;
    const float av = a[gp];
    const float s = 1.0f / (1.0f + DT * DT * av);
    const float sc = DT * s;
    const float bb = bB[gp];
#pragma unroll
    for (int mi = 0; mi < 4; ++mi) {
      const int gm = m0 + wm + mi * 16 + quad * 4;
#pragma unroll
      for (int r2 = 0; r2 < 4; ++r2)
        fx[(size_t)(gm + r2) * Q_SZ + gp] = sc * (acc[mi][ni][r2] + bb);
    }
  }
}

__global__ __launch_bounds__(256) void gemm2_kernel(
    const float* __restrict__ y, const float* __restrict__ WC,
    const float* __restrict__ u, const float* __restrict__ WD,
    const float* __restrict__ bC, const float* __restrict__ bD,
    float* __restrict__ out0) {
  __shared__ __align__(16) bf16_t As[128 * LDST];
  __shared__ __align__(16) bf16_t Bs[128 * LDST];
  const int t = threadIdx.x;
  const int m0 = blockIdx.x * 128, n0 = blockIdx.y * 128;
  f32x4 acc[4][4] = {};
  kloop(y, WC, m0, n0, t, As, Bs, acc);
  kloop(u, WD, m0, n0, t, As, Bs, acc);

  const int lane = t & 63, ln = lane & 15, quad = lane >> 4;
  const int wave = t >> 6;
  const int wm = (wave & 1) * 64, wn = (wave >> 1) * 64;
#pragma unroll
  for (int ni = 0; ni < 4; ++ni) {
    const int gp = n0 + wn + ni * 16 + ln;
    const float bias = bC[gp] + bD[gp];
#pragma unroll
    for (int mi = 0; mi < 4; ++mi) {
      const int gm = m0 + wm + mi * 16 + quad * 4;
#pragma unroll
      for (int r2 = 0; r2 < 4; ++r2) {
        const float x = acc[mi][ni][r2] + bias;
        const float g = 0.5f * x * (1.0f + erff(x * 0.70710678118654752f));
        const float sg = 1.0f / (1.0f + __expf(-g));
        const float uu = u[(size_t)(gm + r2) * Q_SZ + gp];
        out0[(size_t)(gm + r2) * Q_SZ + gp] = fmaf(g, sg, uu);
      }
    }
  }
}

__global__ __launch_bounds__(256) void scan1_kernel(
    const float* __restrict__ fx, const float* __restrict__ a,
    float* __restrict__ ex, float* __restrict__ ez) {
  const int g = blockIdx.x * 256 + threadIdx.x;
  const int p = g & 255, c = (g >> 8) & (CHUNKS - 1), b = g >> 14;
  const float av = a[p];
  const float s = 1.0f / (1.0f + DT * DT * av);
  const float dsa = DT * s * av, dss = DT * s;
  float x = 0.f, z = 0.f;
  const float* fp = fx + ((size_t)b * N_SZ + c * CLEN) * Q_SZ + p;
  for (int n = 0; n < CLEN; ++n) {
    const float f = fp[(size_t)n * Q_SZ];
    const float xn = fmaf(s, x, fmaf(-dsa, z, f));
    const float zn = fmaf(dss, x, fmaf(s, z, DT * f));
    x = xn; z = zn;
  }
  ex[g] = x; ez[g] = z;
}

__global__ __launch_bounds__(256) void scan3_kernel(
    const float* __restrict__ a, const float* __restrict__ ix,
    const float* __restrict__ iz, float* __restrict__ yf) {
  const int g = blockIdx.x * 256 + threadIdx.x;
  const int p = g & 255, c = (g >> 8) & (CHUNKS - 1), b = g >> 14;
  const float av = a[p];
  const float s = 1.0f / (1.0f + DT * DT * av);
  const float dsa = DT * s * av, dss = DT * s;
  float x = ix[g], z = iz[g];
  float* yp = yf + ((size_t)b * N_SZ + c * CLEN) * Q_SZ + p;
  for (int n = 0; n < CLEN; ++n) {
    const float f = yp[(size_t)n * Q_SZ];
    const float xn = fmaf(s, x, fmaf(-dsa, z, f));
    const float zn = fmaf(dss, x, fmaf(s, z, DT * f));
    x = xn; z = zn;
    yp[(size_t)n * Q_SZ] = zn;
  }
}

__global__ __launch_bounds__(256) void scan_mono_kernel(
    const float* __restrict__ a, float* __restrict__ yf) {
  const int g = blockIdx.x * 256 + threadIdx.x;
  const int p = g & 255, b = g >> 8;
  const float av = a[p];
  const float s = 1.0f / (1.0f + DT * DT * av);
  const float dsa = DT * s * av, dss = DT * s;
  float x = 0.f, z = 0.f;
  float* yp = yf + (size_t)b * N_SZ * Q_SZ + p;
  for (int n = 0; n < N_SZ; ++n) {
    const float f = yp[(size_t)n * Q_SZ];
    const float xn = fmaf(s, x, fmaf(-dsa, z, f));
    const float zn = fmaf(dss, x, fmaf(s, z, DT * f));
    x = xn; z = zn;
    yp[(size_t)n * Q_SZ] = zn;
  }
}

// ---------------- launcher ----------------

extern "C" void kernel_launch(void* const* d_in, const int* in_sizes, int n_in,
                              void* d_out, int out_size, void* d_ws, size_t ws_size,
                              hipStream_t stream) {
  const float* u  = (const float*)d_in[0];
  const float* a  = (const float*)d_in[1];
  const float* WB = (const float*)d_in[2];
  const float* bB = (const float*)d_in[3];
  const float* WC = (const float*)d_in[4];
  const float* bC = (const float*)d_in[5];
  const float* WD = (const float*)d_in[6];
  const float* bD = (const float*)d_in[7];

  float* out0 = (float*)d_out;                // first 16.7M fp32: out
  float* yreg = out0 + (size_t)M_TOT * Q_SZ;  // second 16.7M fp32: lz -> y

  const size_t UB_ELEMS = (size_t)M_TOT * Q_SZ;  // 16,777,216
  const size_t W_ELEMS = (size_t)Q_SZ * Q_SZ;    // 65,536
  const size_t ST_ELEMS = (size_t)B_SZ * CHUNKS * Q_SZ; // 262,144
  const size_t need_full =
      UB_ELEMS * sizeof(bf16_t) +              // ubP
      UB_ELEMS * sizeof(bf16_t) +              // ybP
      3 * W_ELEMS * sizeof(bf16_t) +           // weights
      4 * ST_ELEMS * sizeof(float) +           // ex/ez/ix/iz
      2 * 64 * 256 * sizeof(float);            // t10/t11  (~71.6 MB)
  const size_t state_bytes = 4 * ST_ELEMS * sizeof(float); // 4 MiB

  if (ws_size >= need_full) {
    bf16_t* ubP  = (bf16_t*)d_ws;
    bf16_t* ybP  = ubP + UB_ELEMS;
    bf16_t* WBbP = ybP + UB_ELEMS;
    bf16_t* WCbP = WBbP + W_ELEMS;
    bf16_t* WDbP = WCbP + W_ELEMS;
    float* ex = (float*)(WDbP + W_ELEMS);
    float* ez = ex + ST_ELEMS;
    float* ix = ez + ST_ELEMS;
    float* iz = ix + ST_ELEMS;
    float* t10 = iz + ST_ELEMS;
    float* t11 = t10 + 64 * 256;

    prep_kernel<<<8288, 256, 0, stream>>>(u, WB, WC, WD, ubP, WBbP, WCbP, WDbP);
    gemm1f_kernel<<<1024, 256, 0, stream>>>(ubP, WBbP, a, bB, ex, ez, yreg);
    scan2_kernel<<<16, 256, 0, stream>>>(a, ex, ez, ix, iz);
    mpow_kernel<<<1, 256, 0, stream>>>(a, t10, t11);
    fix3_kernel<<<8192, 256, 0, stream>>>(ix, iz, t10, t11, yreg, ybP);
    gemm2p_kernel<<<1024, 256, 0, stream>>>(ybP, WCbP, ubP, WDbP, u, bC, bD, out0);
  } else {
    dim3 gg(M_TOT / 128, Q_SZ / 128);
    gemm1_kernel<<<gg, 256, 0, stream>>>(u, WB, a, bB, yreg);
    if (ws_size >= state_bytes) {
      float* ex = (float*)d_ws;
      float* ez = ex + ST_ELEMS;
      float* ix = ez + ST_ELEMS;
      float* iz = ix + ST_ELEMS;
      scan1_kernel<<<1024, 256, 0, stream>>>(yreg, a, ex, ez);
      scan2_kernel<<<16, 256, 0, stream>>>(a, ex, ez, ix, iz);
      scan3_kernel<<<1024, 256, 0, stream>>>(a, ix, iz, yreg);
    } else {
      scan_mono_kernel<<<16, 256, 0, stream>>>(a, yreg);
    }
    gemm2_kernel<<<gg, 256, 0, stream>>>(yreg, WC, u, WD, bC, bD, out0);
  }
}